// Round 1
// baseline (265.952 us; speedup 1.0000x reference)
//
#include <hip/hip_runtime.h>
#include <math.h>

#define EPS 1e-5f
// B=32, N=4096, C=96, H=192

__device__ __forceinline__ float2 cmulf(float2 a, float c, float s) {
    return make_float2(a.x * c - a.y * s, a.x * s + a.y * c);
}

// ---------------------------------------------------------------------------
// GEMM1: h_t[b][hc][n] = relu(bn1( sum_c x[b][n][c] * w1[hc][c] ))
// grid (N/64, H/96=2, B), block 256
// ---------------------------------------------------------------------------
__global__ __launch_bounds__(256) void gemm1_kernel(
    const float* __restrict__ x,    // [B,4096,96]
    const float* __restrict__ w1,   // [192,96]
    const float* __restrict__ g1, const float* __restrict__ be1,
    const float* __restrict__ mu1, const float* __restrict__ va1,
    float* __restrict__ ht)         // [B,192,4096]
{
    __shared__ float xs[96 * 65];   // [c][t] padded
    __shared__ float w1s[96 * 97];  // [c][ch] padded

    const int tid = threadIdx.x;
    const int n0 = blockIdx.x * 64;
    const int h0 = blockIdx.y * 96;
    const int b  = blockIdx.z;

    const float* xb = x + ((size_t)b * 4096 + n0) * 96;

    // load x tile: 64 tokens x 96 c  (1536 float4)
    #pragma unroll
    for (int i = 0; i < 6; ++i) {
        int id = tid + i * 256;
        int t = id / 24, c4 = (id % 24) * 4;
        float4 v = *(const float4*)(xb + t * 96 + c4);
        xs[(c4 + 0) * 65 + t] = v.x;
        xs[(c4 + 1) * 65 + t] = v.y;
        xs[(c4 + 2) * 65 + t] = v.z;
        xs[(c4 + 3) * 65 + t] = v.w;
    }
    // load w1 half: 96 ch x 96 c (2304 float4), transposed into [c][ch]
    #pragma unroll
    for (int i = 0; i < 9; ++i) {
        int id = tid + i * 256;
        int ch = id / 24, c4 = (id % 24) * 4;
        float4 v = *(const float4*)(w1 + (size_t)(h0 + ch) * 96 + c4);
        w1s[(c4 + 0) * 97 + ch] = v.x;
        w1s[(c4 + 1) * 97 + ch] = v.y;
        w1s[(c4 + 2) * 97 + ch] = v.z;
        w1s[(c4 + 3) * 97 + ch] = v.w;
    }
    __syncthreads();

    const int tx = tid & 15;   // token group: n = n0 + tx + 16*i (write-coalesced)
    const int ty = tid >> 4;   // channel group: ch = ty*6 + j

    float acc[4][6];
    #pragma unroll
    for (int i = 0; i < 4; ++i)
        #pragma unroll
        for (int j = 0; j < 6; ++j) acc[i][j] = 0.f;

    for (int c = 0; c < 96; ++c) {
        float xv[4], wv[6];
        #pragma unroll
        for (int i = 0; i < 4; ++i) xv[i] = xs[c * 65 + tx + 16 * i];
        #pragma unroll
        for (int j = 0; j < 6; ++j) wv[j] = w1s[c * 97 + ty * 6 + j];
        #pragma unroll
        for (int i = 0; i < 4; ++i)
            #pragma unroll
            for (int j = 0; j < 6; ++j)
                acc[i][j] = fmaf(xv[i], wv[j], acc[i][j]);
    }

    #pragma unroll
    for (int j = 0; j < 6; ++j) {
        int hc = h0 + ty * 6 + j;
        float s  = g1[hc] * rsqrtf(va1[hc] + EPS);
        float bb = be1[hc] - mu1[hc] * s;
        float* dst = ht + ((size_t)b * 192 + hc) * 4096 + n0;
        #pragma unroll
        for (int i = 0; i < 4; ++i) {
            float v = fmaf(acc[i][j], s, bb);
            dst[tx + 16 * i] = fmaxf(v, 0.f);
        }
    }
}

// ---------------------------------------------------------------------------
// Radix-4 Stockham, 6 stages, unnormalized. SIGN=-1 fwd, +1 inv.
// data lives in (cur ? bB : bA) on entry; cur toggled per stage.
// Caller must __syncthreads() after return before reading the result.
// ---------------------------------------------------------------------------
template <int SIGN>
__device__ __forceinline__ void fft_stages(float2* bA, float2* bB, int& cur, int tid)
{
    #pragma unroll 1
    for (int s = 0; s < 6; ++s) {
        const int Ns = 1 << (2 * s);
        float2* __restrict__ src = cur ? bB : bA;
        float2* __restrict__ dst = cur ? bA : bB;
        __syncthreads();
        #pragma unroll
        for (int q = 0; q < 4; ++q) {
            const int j = q * 256 + tid;          // 0..1023
            float2 v0 = src[j];
            float2 v1 = src[j + 1024];
            float2 v2 = src[j + 2048];
            float2 v3 = src[j + 3072];
            const int jm = j & (Ns - 1);
            if (Ns > 1) {
                float ang = (float)SIGN * 6.28318530717958647692f *
                            (float)jm / (float)(4 * Ns);
                float s1, c1;
                __sincosf(ang, &s1, &c1);
                float c2 = c1 * c1 - s1 * s1, s2 = 2.f * c1 * s1;
                float c3 = c1 * c2 - s1 * s2, s3 = c1 * s2 + s1 * c2;
                v1 = cmulf(v1, c1, s1);
                v2 = cmulf(v2, c2, s2);
                v3 = cmulf(v3, c3, s3);
            }
            float t0x = v0.x + v2.x, t0y = v0.y + v2.y;
            float t1x = v0.x - v2.x, t1y = v0.y - v2.y;
            float t2x = v1.x + v3.x, t2y = v1.y + v3.y;
            float t3x = v1.x - v3.x, t3y = v1.y - v3.y;
            const float sg = (float)SIGN;
            float2 X0 = make_float2(t0x + t2x, t0y + t2y);
            float2 X2 = make_float2(t0x - t2x, t0y - t2y);
            float2 X1 = make_float2(t1x - sg * t3y, t1y + sg * t3x);
            float2 X3 = make_float2(t1x + sg * t3y, t1y - sg * t3x);
            const int idxD = ((j >> (2 * s)) << (2 * s + 2)) + jm;
            dst[idxD]          = X0;
            dst[idxD + Ns]     = X1;
            dst[idxD + 2 * Ns] = X2;
            dst[idxD + 3 * Ns] = X3;
        }
        cur ^= 1;
    }
}

// ---------------------------------------------------------------------------
// FFT middle kernel: per (b, channel-pair). Packs two real rows as one
// complex FFT, Hermitian-unpacks, applies relu'd diagonal mix at k and N-k,
// Hermitian-symmetrizes, one inverse FFT gives both real outputs.
// grid (H/2=96, B), block 256, static LDS 64 KB.
// ---------------------------------------------------------------------------
__global__ __launch_bounds__(256) void fft_mid_kernel(
    float* __restrict__ ht,          // [B,192,4096] in/out
    const float* __restrict__ rmat,  // [192,192]
    const float* __restrict__ imat,  // [192,192]
    const float* __restrict__ rb,    // [192]
    const float* __restrict__ ib)    // [192]
{
    __shared__ float2 bA[4096];
    __shared__ float2 bB[4096];

    const int tid = threadIdx.x;
    const int p   = blockIdx.x;
    const int b   = blockIdx.y;
    const int h1  = 2 * p, h2 = 2 * p + 1;
    float* row1 = ht + ((size_t)b * 192 + h1) * 4096;
    float* row2 = ht + ((size_t)b * 192 + h2) * 4096;

    // pack two real rows into one complex buffer
    #pragma unroll
    for (int i = 0; i < 16; ++i) {
        int n = tid + i * 256;
        bA[n] = make_float2(row1[n], row2[n]);
    }

    int cur = 0;
    fft_stages<-1>(bA, bB, cur, tid);   // forward, ends with data in bA (cur=0)
    __syncthreads();

    const float rd1 = rmat[(size_t)h1 * 192 + h1], ig1 = imat[(size_t)h1 * 192 + h1];
    const float rd2 = rmat[(size_t)h2 * 192 + h2], ig2 = imat[(size_t)h2 * 192 + h2];
    const float rb1 = rb[h1], ib1 = ib[h1];
    const float rb2 = rb[h2], ib2 = ib[h2];

    float2* F  = cur ? bB : bA;
    float2* Gd = cur ? bA : bB;
    for (int k = tid; k <= 2048; k += 256) {
        int m = (4096 - k) & 4095;
        float2 Fk = F[k], Fm = F[m];
        const float sc = 1.f / 128.f;   // 0.5 (unpack) * 1/64 (ortho fwd)
        float X1r = sc * (Fk.x + Fm.x), X1i = sc * (Fk.y - Fm.y);
        float X2r = sc * (Fk.y + Fm.y), X2i = sc * (Fm.x - Fk.x);
        // channel 1 at k and mirror m (X1[m] = conj(X1[k]))
        float Z1kr = fmaxf(fmaf(X1r, rd1, fmaf(-X1i, ig1, rb1)), 0.f);
        float Z1ki = fmaxf(fmaf(X1i, rd1, fmaf( X1r, ig1, ib1)), 0.f);
        float Z1mr = fmaxf(fmaf(X1r, rd1, fmaf( X1i, ig1, rb1)), 0.f);
        float Z1mi = fmaxf(fmaf(-X1i, rd1, fmaf(X1r, ig1, ib1)), 0.f);
        // channel 2
        float Z2kr = fmaxf(fmaf(X2r, rd2, fmaf(-X2i, ig2, rb2)), 0.f);
        float Z2ki = fmaxf(fmaf(X2i, rd2, fmaf( X2r, ig2, ib2)), 0.f);
        float Z2mr = fmaxf(fmaf(X2r, rd2, fmaf( X2i, ig2, rb2)), 0.f);
        float Z2mi = fmaxf(fmaf(-X2i, rd2, fmaf(X2r, ig2, ib2)), 0.f);
        // G = herm(Z1) + i*herm(Z2)  (0.5 factor of hermitianization)
        float Gkx = 0.5f * ((Z1kr + Z1mr) - (Z2ki - Z2mi));
        float Gky = 0.5f * ((Z1ki - Z1mi) + (Z2kr + Z2mr));
        float Gmx = 0.5f * ((Z1mr + Z1kr) - (Z2mi - Z2ki));
        float Gmy = 0.5f * ((Z1mi - Z1ki) + (Z2mr + Z2kr));
        Gd[k] = make_float2(Gkx, Gky);
        Gd[m] = make_float2(Gmx, Gmy);
    }
    cur ^= 1;                            // data now in Gd

    fft_stages<1>(bA, bB, cur, tid);     // inverse (unnormalized)
    __syncthreads();

    float2* Y = cur ? bB : bA;
    const float inv = 1.f / 64.f;        // ortho inverse scale
    #pragma unroll
    for (int i = 0; i < 16; ++i) {
        int n = tid + i * 256;
        float2 g = Y[n];
        row1[n] = g.x * inv;
        row2[n] = g.y * inv;
    }
}

// ---------------------------------------------------------------------------
// GEMM2: out[b][n][c] = bn2( sum_hc y_t[b][hc][n] * w2[c][hc] )
// grid (N/64, B), block 256
// ---------------------------------------------------------------------------
__global__ __launch_bounds__(256) void gemm2_kernel(
    const float* __restrict__ yt,   // [B,192,4096]
    const float* __restrict__ w2,   // [96,192]
    const float* __restrict__ g2, const float* __restrict__ be2,
    const float* __restrict__ mu2, const float* __restrict__ va2,
    float* __restrict__ out)        // [B,4096,96]
{
    __shared__ float ys[96 * 64];   // [kc][t], linear (matches global layout)
    __shared__ float w2s[96 * 97];  // [kc][c] padded

    const int tid = threadIdx.x;
    const int n0 = blockIdx.x * 64;
    const int b  = blockIdx.y;

    const int tx = tid & 15;   // out-channel group: c = tx + 16*j (write-coalesced)
    const int ty = tid >> 4;   // token group: n = n0 + ty*4 + i

    float acc[4][6];
    #pragma unroll
    for (int i = 0; i < 4; ++i)
        #pragma unroll
        for (int j = 0; j < 6; ++j) acc[i][j] = 0.f;

    for (int kh = 0; kh < 2; ++kh) {
        __syncthreads();
        // y tile: 96 kc x 64 tokens (layout matches global -> float4 straight in)
        #pragma unroll
        for (int i2 = 0; i2 < 6; ++i2) {
            int id = tid + i2 * 256;
            int kc = id / 16, t4 = (id % 16) * 4;
            float4 v = *(const float4*)(yt + ((size_t)b * 192 + kh * 96 + kc) * 4096 + n0 + t4);
            *(float4*)&ys[kc * 64 + t4] = v;
        }
        // w2 tile transposed: [kc][c]
        #pragma unroll
        for (int i2 = 0; i2 < 9; ++i2) {
            int id = tid + i2 * 256;
            int c = id / 24, k4 = (id % 24) * 4;
            float4 v = *(const float4*)(w2 + (size_t)c * 192 + kh * 96 + k4);
            w2s[(k4 + 0) * 97 + c] = v.x;
            w2s[(k4 + 1) * 97 + c] = v.y;
            w2s[(k4 + 2) * 97 + c] = v.z;
            w2s[(k4 + 3) * 97 + c] = v.w;
        }
        __syncthreads();

        for (int kc = 0; kc < 96; ++kc) {
            float4 yv4 = *(const float4*)&ys[kc * 64 + ty * 4];
            float yv[4] = {yv4.x, yv4.y, yv4.z, yv4.w};
            float wv[6];
            #pragma unroll
            for (int j = 0; j < 6; ++j) wv[j] = w2s[kc * 97 + tx + 16 * j];
            #pragma unroll
            for (int i = 0; i < 4; ++i)
                #pragma unroll
                for (int j = 0; j < 6; ++j)
                    acc[i][j] = fmaf(yv[i], wv[j], acc[i][j]);
        }
    }

    #pragma unroll
    for (int j = 0; j < 6; ++j) {
        int c = tx + 16 * j;
        float s  = g2[c] * rsqrtf(va2[c] + EPS);
        float bb = be2[c] - mu2[c] * s;
        #pragma unroll
        for (int i = 0; i < 4; ++i) {
            out[((size_t)b * 4096 + n0 + ty * 4 + i) * 96 + c] = fmaf(acc[i][j], s, bb);
        }
    }
}

// ---------------------------------------------------------------------------
extern "C" void kernel_launch(void* const* d_in, const int* in_sizes, int n_in,
                              void* d_out, int out_size, void* d_ws, size_t ws_size,
                              hipStream_t stream)
{
    const float* x   = (const float*)d_in[0];
    const float* w1  = (const float*)d_in[1];
    const float* g1  = (const float*)d_in[2];
    const float* be1 = (const float*)d_in[3];
    const float* mu1 = (const float*)d_in[4];
    const float* va1 = (const float*)d_in[5];
    const float* r   = (const float*)d_in[6];
    const float* im  = (const float*)d_in[7];
    const float* rb  = (const float*)d_in[8];
    const float* ib  = (const float*)d_in[9];
    const float* w2  = (const float*)d_in[10];
    const float* g2  = (const float*)d_in[11];
    const float* be2 = (const float*)d_in[12];
    const float* mu2 = (const float*)d_in[13];
    const float* va2 = (const float*)d_in[14];
    float* out = (float*)d_out;

    float* ht = (float*)d_ws;   // [32][192][4096] fp32 = 100.7 MB scratch

    gemm1_kernel<<<dim3(64, 2, 32), 256, 0, stream>>>(x, w1, g1, be1, mu1, va1, ht);
    fft_mid_kernel<<<dim3(96, 32), 256, 0, stream>>>(ht, r, im, rb, ib);
    gemm2_kernel<<<dim3(64, 32), 256, 0, stream>>>(ht, w2, g2, be2, mu2, va2, out);
}

// Round 2
// 233.668 us; speedup vs baseline: 1.1382x; 1.1382x over previous
//
#include <hip/hip_runtime.h>
#include <math.h>

#define EPS 1e-5f
// B=32, N=4096, C=96, H=192

__device__ __forceinline__ float2 cmul(float2 a, float c, float s) {
    // a * (c + i s)
    return make_float2(a.x * c - a.y * s, a.x * s + a.y * c);
}
__device__ __forceinline__ float2 cmulc(float2 a, float2 b) {
    return make_float2(a.x * b.x - a.y * b.y, a.x * b.y + a.y * b.x);
}

// ---------------------------------------------------------------------------
// GEMM1: h_t[b][hc][n] = relu(bn1( sum_c x[b][n][c] * w1[hc][c] ))
// grid (N/64, H/96=2, B), block 256
// ---------------------------------------------------------------------------
__global__ __launch_bounds__(256) void gemm1_kernel(
    const float* __restrict__ x,    // [B,4096,96]
    const float* __restrict__ w1,   // [192,96]
    const float* __restrict__ g1, const float* __restrict__ be1,
    const float* __restrict__ mu1, const float* __restrict__ va1,
    float* __restrict__ ht)         // [B,192,4096]
{
    __shared__ float xs[96 * 65];   // [c][t] padded
    __shared__ float w1s[96 * 97];  // [c][ch] padded

    const int tid = threadIdx.x;
    const int n0 = blockIdx.x * 64;
    const int h0 = blockIdx.y * 96;
    const int b  = blockIdx.z;

    const float* xb = x + ((size_t)b * 4096 + n0) * 96;

    #pragma unroll
    for (int i = 0; i < 6; ++i) {
        int id = tid + i * 256;
        int t = id / 24, c4 = (id % 24) * 4;
        float4 v = *(const float4*)(xb + t * 96 + c4);
        xs[(c4 + 0) * 65 + t] = v.x;
        xs[(c4 + 1) * 65 + t] = v.y;
        xs[(c4 + 2) * 65 + t] = v.z;
        xs[(c4 + 3) * 65 + t] = v.w;
    }
    #pragma unroll
    for (int i = 0; i < 9; ++i) {
        int id = tid + i * 256;
        int ch = id / 24, c4 = (id % 24) * 4;
        float4 v = *(const float4*)(w1 + (size_t)(h0 + ch) * 96 + c4);
        w1s[(c4 + 0) * 97 + ch] = v.x;
        w1s[(c4 + 1) * 97 + ch] = v.y;
        w1s[(c4 + 2) * 97 + ch] = v.z;
        w1s[(c4 + 3) * 97 + ch] = v.w;
    }
    __syncthreads();

    const int tx = tid & 15;
    const int ty = tid >> 4;

    float acc[4][6];
    #pragma unroll
    for (int i = 0; i < 4; ++i)
        #pragma unroll
        for (int j = 0; j < 6; ++j) acc[i][j] = 0.f;

    for (int c = 0; c < 96; ++c) {
        float xv[4], wv[6];
        #pragma unroll
        for (int i = 0; i < 4; ++i) xv[i] = xs[c * 65 + tx + 16 * i];
        #pragma unroll
        for (int j = 0; j < 6; ++j) wv[j] = w1s[c * 97 + ty * 6 + j];
        #pragma unroll
        for (int i = 0; i < 4; ++i)
            #pragma unroll
            for (int j = 0; j < 6; ++j)
                acc[i][j] = fmaf(xv[i], wv[j], acc[i][j]);
    }

    #pragma unroll
    for (int j = 0; j < 6; ++j) {
        int hc = h0 + ty * 6 + j;
        float s  = g1[hc] * rsqrtf(va1[hc] + EPS);
        float bb = be1[hc] - mu1[hc] * s;
        float* dst = ht + ((size_t)b * 192 + hc) * 4096 + n0;
        #pragma unroll
        for (int i = 0; i < 4; ++i) {
            float v = fmaf(acc[i][j], s, bb);
            dst[tx + 16 * i] = fmaxf(v, 0.f);
        }
    }
}

// ---------------------------------------------------------------------------
// Radix-16 register FFT over N=4096 with 256 threads, 16 complex per thread.
// Decomposition: n = 256a + t;  t = t1 + 16 t2;  output k = r + 16 m + 256 p.
// NB holds natural-order data under nibble-XOR swizzle NBIDX; LX is the
// exchange buffer. Both 4096 float2 (32 KB each).
// ---------------------------------------------------------------------------
#define NBIDX(k) ((((k) & 0x0FF0)) | (((k) ^ ((k) >> 4)) & 0x0F))

// 16-point DFT, sign S (-1 fwd, +1 inv): v[r] = sum_a v_in[a] e^{S 2pi i a r/16}
template <int S>
__device__ __forceinline__ void dft16(float2 v[16]) {
    const float sg = (float)S;
    const float C1 = 0.92387953251128675613f; // cos(pi/8)
    const float S1 = 0.38268343236508977173f; // sin(pi/8)
    const float R  = 0.70710678118654752440f; // sqrt(2)/2
    float2 g[16];
    #pragma unroll
    for (int a1 = 0; a1 < 4; ++a1) {
        float2 v0 = v[a1], v1 = v[a1 + 4], v2 = v[a1 + 8], v3 = v[a1 + 12];
        float t0x = v0.x + v2.x, t0y = v0.y + v2.y;
        float t1x = v0.x - v2.x, t1y = v0.y - v2.y;
        float t2x = v1.x + v3.x, t2y = v1.y + v3.y;
        float t3x = v1.x - v3.x, t3y = v1.y - v3.y;
        g[0 * 4 + a1] = make_float2(t0x + t2x, t0y + t2y);
        g[1 * 4 + a1] = make_float2(t1x - sg * t3y, t1y + sg * t3x);
        g[2 * 4 + a1] = make_float2(t0x - t2x, t0y - t2y);
        g[3 * 4 + a1] = make_float2(t1x + sg * t3y, t1y - sg * t3x);
    }
    // twiddles omega16^{a1*r1} applied to g[r1*4 + a1]
    g[4 + 1]  = cmul(g[4 + 1],  C1,  sg * S1);           // k=1
    g[4 + 2]  = cmul(g[4 + 2],  R,   sg * R);            // k=2
    g[4 + 3]  = cmul(g[4 + 3],  S1,  sg * C1);           // k=3
    g[8 + 1]  = cmul(g[8 + 1],  R,   sg * R);            // k=2
    {   // k=4: multiply by S*i
        float2 a = g[8 + 2];
        g[8 + 2] = make_float2(-sg * a.y, sg * a.x);
    }
    g[8 + 3]  = cmul(g[8 + 3],  -R,  sg * R);            // k=6
    g[12 + 1] = cmul(g[12 + 1], S1,  sg * C1);           // k=3
    g[12 + 2] = cmul(g[12 + 2], -R,  sg * R);            // k=6
    g[12 + 3] = cmul(g[12 + 3], -C1, -sg * S1);          // k=9
    #pragma unroll
    for (int r1 = 0; r1 < 4; ++r1) {
        float2 v0 = g[r1 * 4 + 0], v1 = g[r1 * 4 + 1],
               v2 = g[r1 * 4 + 2], v3 = g[r1 * 4 + 3];
        float t0x = v0.x + v2.x, t0y = v0.y + v2.y;
        float t1x = v0.x - v2.x, t1y = v0.y - v2.y;
        float t2x = v1.x + v3.x, t2y = v1.y + v3.y;
        float t3x = v1.x - v3.x, t3y = v1.y - v3.y;
        v[r1 + 0]  = make_float2(t0x + t2x, t0y + t2y);
        v[r1 + 4]  = make_float2(t1x - sg * t3y, t1y + sg * t3x);
        v[r1 + 8]  = make_float2(t0x - t2x, t0y - t2y);
        v[r1 + 12] = make_float2(t1x + sg * t3y, t1y - sg * t3x);
    }
}

// Build W[j] = w^j for j=1..15 from w, log-depth ladder.
__device__ __forceinline__ void twiddle_ladder(float2 w, float2 W[16]) {
    W[1] = w;
    W[2] = cmulc(W[1], W[1]);
    W[3] = cmulc(W[2], W[1]);
    W[4] = cmulc(W[2], W[2]);
    W[5] = cmulc(W[4], W[1]);
    W[6] = cmulc(W[4], W[2]);
    W[7] = cmulc(W[4], W[3]);
    W[8] = cmulc(W[4], W[4]);
    #pragma unroll
    for (int j = 1; j < 8; ++j) W[8 + j] = cmulc(W[8], W[j]);
}

template <int S>
__device__ __forceinline__ void fft4096(float2* __restrict__ NB,
                                        float2* __restrict__ LX, int tid)
{
    const float TWO_PI = 6.28318530717958647692f;
    float2 v[16];
    // ---- pass A: 16-pt DFT over a (stride 256), twiddle w4096^{t*r} ----
    {
        const int ii = (tid & 0xF0) | ((tid ^ (tid >> 4)) & 0x0F);
        #pragma unroll
        for (int a = 0; a < 16; ++a) v[a] = NB[a * 256 + ii];
        dft16<S>(v);
        float c0, s0;
        __sincosf((float)S * TWO_PI * (float)tid * (1.f / 4096.f), &s0, &c0);
        float2 W[16];
        twiddle_ladder(make_float2(c0, s0), W);
        #pragma unroll
        for (int r2 = 1; r2 < 16; ++r2) v[r2] = cmulc(v[r2], W[r2]);
        #pragma unroll
        for (int r2 = 0; r2 < 16; ++r2) LX[r2 * 256 + tid] = v[r2];
    }
    __syncthreads();
    // ---- pass B: 16-pt DFT over t2, twiddle w256^{t1*m} ----
    const int r = tid >> 4, t1 = tid & 15;
    {
        #pragma unroll
        for (int t2 = 0; t2 < 16; ++t2) v[t2] = LX[r * 256 + t2 * 16 + t1];
        dft16<S>(v);
        float c0, s0;
        __sincosf((float)S * TWO_PI * (float)t1 * (1.f / 256.f), &s0, &c0);
        float2 W[16];
        twiddle_ladder(make_float2(c0, s0), W);
        #pragma unroll
        for (int m = 1; m < 16; ++m) v[m] = cmulc(v[m], W[m]);
        __syncthreads();   // all reads of LX done before aliased overwrite
        #pragma unroll
        for (int m = 0; m < 16; ++m) LX[r * 256 + m * 16 + (t1 ^ m)] = v[m];
    }
    __syncthreads();
    // ---- pass C: 16-pt DFT over t1, output k = r + 16m + 256p ----
    {
        const int m = tid & 15;
        #pragma unroll
        for (int q = 0; q < 16; ++q) v[q] = LX[r * 256 + m * 16 + (q ^ m)];
        dft16<S>(v);
        const int inner = (m * 16) | ((r ^ m) & 15);   // NBIDX(r + 16m)
        #pragma unroll
        for (int p = 0; p < 16; ++p) NB[p * 256 + inner] = v[p];
    }
    __syncthreads();
}

// ---------------------------------------------------------------------------
// FFT middle kernel: per (b, channel-pair). grid (96, 32), block 256.
// ---------------------------------------------------------------------------
__global__ __launch_bounds__(256) void fft_mid_kernel(
    float* __restrict__ ht,          // [B,192,4096] in/out
    const float* __restrict__ rmat,  // [192,192]
    const float* __restrict__ imat,  // [192,192]
    const float* __restrict__ rb,    // [192]
    const float* __restrict__ ib)    // [192]
{
    __shared__ float2 NB[4096];
    __shared__ float2 LX[4096];

    const int tid = threadIdx.x;
    const int pp  = blockIdx.x;
    const int b   = blockIdx.y;
    const int h1  = 2 * pp, h2 = 2 * pp + 1;
    float* row1 = ht + ((size_t)b * 192 + h1) * 4096;
    float* row2 = ht + ((size_t)b * 192 + h2) * 4096;

    // pack two real rows into one complex buffer (swizzled natural order)
    const int ii = (tid & 0xF0) | ((tid ^ (tid >> 4)) & 0x0F);
    #pragma unroll
    for (int a = 0; a < 16; ++a) {
        int n = a * 256 + tid;
        NB[a * 256 + ii] = make_float2(row1[n], row2[n]);
    }
    __syncthreads();

    fft4096<-1>(NB, LX, tid);   // forward; spectrum in NB (swizzled natural)

    const float rd1 = rmat[(size_t)h1 * 192 + h1], ig1 = imat[(size_t)h1 * 192 + h1];
    const float rd2 = rmat[(size_t)h2 * 192 + h2], ig2 = imat[(size_t)h2 * 192 + h2];
    const float rb1 = rb[h1], ib1 = ib[h1];
    const float rb2 = rb[h2], ib2 = ib[h2];

    for (int k = tid; k <= 2048; k += 256) {
        int m = (4096 - k) & 4095;
        float2 Fk = NB[NBIDX(k)], Fm = NB[NBIDX(m)];
        const float sc = 1.f / 128.f;   // 0.5 (unpack) * 1/64 (ortho fwd)
        float X1r = sc * (Fk.x + Fm.x), X1i = sc * (Fk.y - Fm.y);
        float X2r = sc * (Fk.y + Fm.y), X2i = sc * (Fm.x - Fk.x);
        float Z1kr = fmaxf(fmaf(X1r, rd1, fmaf(-X1i, ig1, rb1)), 0.f);
        float Z1ki = fmaxf(fmaf(X1i, rd1, fmaf( X1r, ig1, ib1)), 0.f);
        float Z1mr = fmaxf(fmaf(X1r, rd1, fmaf( X1i, ig1, rb1)), 0.f);
        float Z1mi = fmaxf(fmaf(-X1i, rd1, fmaf(X1r, ig1, ib1)), 0.f);
        float Z2kr = fmaxf(fmaf(X2r, rd2, fmaf(-X2i, ig2, rb2)), 0.f);
        float Z2ki = fmaxf(fmaf(X2i, rd2, fmaf( X2r, ig2, ib2)), 0.f);
        float Z2mr = fmaxf(fmaf(X2r, rd2, fmaf( X2i, ig2, rb2)), 0.f);
        float Z2mi = fmaxf(fmaf(-X2i, rd2, fmaf(X2r, ig2, ib2)), 0.f);
        float Gkx = 0.5f * ((Z1kr + Z1mr) - (Z2ki - Z2mi));
        float Gky = 0.5f * ((Z1ki - Z1mi) + (Z2kr + Z2mr));
        float Gmx = 0.5f * ((Z1mr + Z1kr) - (Z2mi - Z2ki));
        float Gmy = 0.5f * ((Z1mi - Z1ki) + (Z2mr + Z2kr));
        NB[NBIDX(k)] = make_float2(Gkx, Gky);
        NB[NBIDX(m)] = make_float2(Gmx, Gmy);
    }
    __syncthreads();

    fft4096<1>(NB, LX, tid);    // inverse (unnormalized); result in NB

    const float inv = 1.f / 64.f;   // ortho inverse scale
    #pragma unroll
    for (int a = 0; a < 16; ++a) {
        int n = a * 256 + tid;
        float2 g = NB[a * 256 + ii];
        row1[n] = g.x * inv;
        row2[n] = g.y * inv;
    }
}

// ---------------------------------------------------------------------------
// GEMM2: out[b][n][c] = bn2( sum_hc y_t[b][hc][n] * w2[c][hc] )
// grid (N/64, B), block 256
// ---------------------------------------------------------------------------
__global__ __launch_bounds__(256) void gemm2_kernel(
    const float* __restrict__ yt,   // [B,192,4096]
    const float* __restrict__ w2,   // [96,192]
    const float* __restrict__ g2, const float* __restrict__ be2,
    const float* __restrict__ mu2, const float* __restrict__ va2,
    float* __restrict__ out)        // [B,4096,96]
{
    __shared__ float ys[96 * 64];
    __shared__ float w2s[96 * 97];

    const int tid = threadIdx.x;
    const int n0 = blockIdx.x * 64;
    const int b  = blockIdx.y;

    const int tx = tid & 15;
    const int ty = tid >> 4;

    float acc[4][6];
    #pragma unroll
    for (int i = 0; i < 4; ++i)
        #pragma unroll
        for (int j = 0; j < 6; ++j) acc[i][j] = 0.f;

    for (int kh = 0; kh < 2; ++kh) {
        __syncthreads();
        #pragma unroll
        for (int i2 = 0; i2 < 6; ++i2) {
            int id = tid + i2 * 256;
            int kc = id / 16, t4 = (id % 16) * 4;
            float4 v = *(const float4*)(yt + ((size_t)b * 192 + kh * 96 + kc) * 4096 + n0 + t4);
            *(float4*)&ys[kc * 64 + t4] = v;
        }
        #pragma unroll
        for (int i2 = 0; i2 < 9; ++i2) {
            int id = tid + i2 * 256;
            int c = id / 24, k4 = (id % 24) * 4;
            float4 v = *(const float4*)(w2 + (size_t)c * 192 + kh * 96 + k4);
            w2s[(k4 + 0) * 97 + c] = v.x;
            w2s[(k4 + 1) * 97 + c] = v.y;
            w2s[(k4 + 2) * 97 + c] = v.z;
            w2s[(k4 + 3) * 97 + c] = v.w;
        }
        __syncthreads();

        for (int kc = 0; kc < 96; ++kc) {
            float4 yv4 = *(const float4*)&ys[kc * 64 + ty * 4];
            float yv[4] = {yv4.x, yv4.y, yv4.z, yv4.w};
            float wv[6];
            #pragma unroll
            for (int j = 0; j < 6; ++j) wv[j] = w2s[kc * 97 + tx + 16 * j];
            #pragma unroll
            for (int i = 0; i < 4; ++i)
                #pragma unroll
                for (int j = 0; j < 6; ++j)
                    acc[i][j] = fmaf(yv[i], wv[j], acc[i][j]);
        }
    }

    #pragma unroll
    for (int j = 0; j < 6; ++j) {
        int c = tx + 16 * j;
        float s  = g2[c] * rsqrtf(va2[c] + EPS);
        float bb = be2[c] - mu2[c] * s;
        #pragma unroll
        for (int i = 0; i < 4; ++i) {
            out[((size_t)b * 4096 + n0 + ty * 4 + i) * 96 + c] = fmaf(acc[i][j], s, bb);
        }
    }
}

// ---------------------------------------------------------------------------
extern "C" void kernel_launch(void* const* d_in, const int* in_sizes, int n_in,
                              void* d_out, int out_size, void* d_ws, size_t ws_size,
                              hipStream_t stream)
{
    const float* x   = (const float*)d_in[0];
    const float* w1  = (const float*)d_in[1];
    const float* g1  = (const float*)d_in[2];
    const float* be1 = (const float*)d_in[3];
    const float* mu1 = (const float*)d_in[4];
    const float* va1 = (const float*)d_in[5];
    const float* r   = (const float*)d_in[6];
    const float* im  = (const float*)d_in[7];
    const float* rb  = (const float*)d_in[8];
    const float* ib  = (const float*)d_in[9];
    const float* w2  = (const float*)d_in[10];
    const float* g2  = (const float*)d_in[11];
    const float* be2 = (const float*)d_in[12];
    const float* mu2 = (const float*)d_in[13];
    const float* va2 = (const float*)d_in[14];
    float* out = (float*)d_out;

    float* ht = (float*)d_ws;   // [32][192][4096] fp32 = 100.7 MB scratch

    gemm1_kernel<<<dim3(64, 2, 32), 256, 0, stream>>>(x, w1, g1, be1, mu1, va1, ht);
    fft_mid_kernel<<<dim3(96, 32), 256, 0, stream>>>(ht, r, im, rb, ib);
    gemm2_kernel<<<dim3(64, 32), 256, 0, stream>>>(ht, w2, g2, be2, mu2, va2, out);
}

// Round 5
// 128.423 us; speedup vs baseline: 2.0709x; 1.8195x over previous
//
#include <hip/hip_runtime.h>
#include <stdint.h>
#include <math.h>

#define EPS 1e-5f
// B=32, N=4096, C=96, H=192

typedef __attribute__((ext_vector_type(8))) short bf16x8;
typedef __attribute__((ext_vector_type(4))) float f32x4;

__device__ __forceinline__ unsigned short f2bf(float f) {
    unsigned u = __float_as_uint(f);
    unsigned r = (u + 0x7FFFu + ((u >> 16) & 1u)) >> 16;
    return (unsigned short)r;
}
__device__ __forceinline__ float bf2f(unsigned short h) {
    return __uint_as_float(((unsigned)h) << 16);
}

__device__ __forceinline__ float2 cmul(float2 a, float c, float s) {
    return make_float2(a.x * c - a.y * s, a.x * s + a.y * c);
}
__device__ __forceinline__ float2 cmulc(float2 a, float2 b) {
    return make_float2(a.x * b.x - a.y * b.y, a.x * b.y + a.y * b.x);
}

// ---------------------------------------------------------------------------
// GEMM1 (MFMA): ht[b][hc][n] = bf16(relu(bn1( sum_c x[b][n][c]*w1[hc][c] )))
// m=hc(192), n=tok(128/block), K=96. grid 1024, block 256 (4 waves).
// LDS k-subtiled [c/8][row][8]; frag reads aligned b128. 62,976 B.
// ---------------------------------------------------------------------------
__global__ __launch_bounds__(256, 2) void gemm1_kernel(
    const float* __restrict__ x,    // [B*4096, 96]
    const float* __restrict__ w1,   // [192, 96]
    const float* __restrict__ g1, const float* __restrict__ be1,
    const float* __restrict__ mu1, const float* __restrict__ va1,
    unsigned short* __restrict__ ht)  // [B,192,4096] bf16
{
    __shared__ unsigned short ws2[12][192][8];  // [c/8][hc][c%8]  36,864 B
    __shared__ unsigned short xs2[12][128][8];  // [c/8][tok][c%8] 24,576 B
    __shared__ float sb[2][192];                //                  1,536 B

    const int tid = threadIdx.x;
    const int T0 = blockIdx.x * 128;
    const int b  = T0 >> 12;
    const int n0 = T0 & 4095;
    const int lane = tid & 63, wid = tid >> 6;
    const int lm = lane & 15, lg = lane >> 4;

    if (tid < 192) {
        float s = g1[tid] * rsqrtf(va1[tid] + EPS);
        sb[0][tid] = s;
        sb[1][tid] = be1[tid] - mu1[tid] * s;
    }
    #pragma unroll
    for (int i = 0; i < 18; ++i) {
        int id = tid + i * 256;             // 4608 float4
        int ch = id / 24, c4 = (id % 24) * 4;
        float4 v = *(const float4*)(w1 + (size_t)ch * 96 + c4);
        ushort4 hv = { f2bf(v.x), f2bf(v.y), f2bf(v.z), f2bf(v.w) };
        *(ushort4*)&ws2[c4 >> 3][ch][c4 & 7] = hv;
    }
    const float* xb = x + (size_t)T0 * 96;
    #pragma unroll
    for (int i = 0; i < 12; ++i) {
        int id = tid + i * 256;             // 3072 float4
        int t = id / 24, c4 = (id % 24) * 4;
        float4 v = *(const float4*)(xb + (size_t)t * 96 + c4);
        ushort4 hv = { f2bf(v.x), f2bf(v.y), f2bf(v.z), f2bf(v.w) };
        *(ushort4*)&xs2[c4 >> 3][t][c4 & 7] = hv;
    }
    __syncthreads();

    const int t0w = wid * 32;
    f32x4 acc[12][2];
    #pragma unroll
    for (int f = 0; f < 12; ++f)
        #pragma unroll
        for (int nf = 0; nf < 2; ++nf) acc[f][nf] = (f32x4){0.f, 0.f, 0.f, 0.f};

    #pragma unroll
    for (int ks = 0; ks < 3; ++ks) {
        const int g = ks * 4 + lg;          // k-group: k = g*8 + j (bijection-safe)
        bf16x8 bfrag[2];
        #pragma unroll
        for (int nf = 0; nf < 2; ++nf)
            bfrag[nf] = *(const bf16x8*)&xs2[g][t0w + nf * 16 + lm][0];
        #pragma unroll
        for (int f = 0; f < 12; ++f) {
            bf16x8 afrag = *(const bf16x8*)&ws2[g][f * 16 + lm][0];
            acc[f][0] = __builtin_amdgcn_mfma_f32_16x16x32_bf16(afrag, bfrag[0], acc[f][0], 0, 0, 0);
            acc[f][1] = __builtin_amdgcn_mfma_f32_16x16x32_bf16(afrag, bfrag[1], acc[f][1], 0, 0, 0);
        }
    }

    unsigned short* hb = ht + (size_t)b * 192 * 4096 + n0;
    #pragma unroll
    for (int f = 0; f < 12; ++f) {
        #pragma unroll
        for (int r = 0; r < 4; ++r) {
            int hc = f * 16 + lg * 4 + r;
            float s = sb[0][hc], bb = sb[1][hc];
            #pragma unroll
            for (int nf = 0; nf < 2; ++nf) {
                float v = fmaxf(fmaf(acc[f][nf][r], s, bb), 0.f);
                hb[(size_t)hc * 4096 + t0w + nf * 16 + lm] = f2bf(v);
            }
        }
    }
}

// ---------------------------------------------------------------------------
// Radix-16 register FFT (N=4096, 256 thr, 16 cplx/thread).
// ---------------------------------------------------------------------------
#define NBIDX(k) ((((k) & 0x0FF0)) | (((k) ^ ((k) >> 4)) & 0x0F))

template <int S>
__device__ __forceinline__ void dft16(float2 v[16]) {
    const float sg = (float)S;
    const float C1 = 0.92387953251128675613f;
    const float S1 = 0.38268343236508977173f;
    const float R  = 0.70710678118654752440f;
    float2 g[16];
    #pragma unroll
    for (int a1 = 0; a1 < 4; ++a1) {
        float2 v0 = v[a1], v1 = v[a1 + 4], v2 = v[a1 + 8], v3 = v[a1 + 12];
        float t0x = v0.x + v2.x, t0y = v0.y + v2.y;
        float t1x = v0.x - v2.x, t1y = v0.y - v2.y;
        float t2x = v1.x + v3.x, t2y = v1.y + v3.y;
        float t3x = v1.x - v3.x, t3y = v1.y - v3.y;
        g[0 * 4 + a1] = make_float2(t0x + t2x, t0y + t2y);
        g[1 * 4 + a1] = make_float2(t1x - sg * t3y, t1y + sg * t3x);
        g[2 * 4 + a1] = make_float2(t0x - t2x, t0y - t2y);
        g[3 * 4 + a1] = make_float2(t1x + sg * t3y, t1y - sg * t3x);
    }
    g[4 + 1]  = cmul(g[4 + 1],  C1,  sg * S1);
    g[4 + 2]  = cmul(g[4 + 2],  R,   sg * R);
    g[4 + 3]  = cmul(g[4 + 3],  S1,  sg * C1);
    g[8 + 1]  = cmul(g[8 + 1],  R,   sg * R);
    {
        float2 a = g[8 + 2];
        g[8 + 2] = make_float2(-sg * a.y, sg * a.x);
    }
    g[8 + 3]  = cmul(g[8 + 3],  -R,  sg * R);
    g[12 + 1] = cmul(g[12 + 1], S1,  sg * C1);
    g[12 + 2] = cmul(g[12 + 2], -R,  sg * R);
    g[12 + 3] = cmul(g[12 + 3], -C1, -sg * S1);
    #pragma unroll
    for (int r1 = 0; r1 < 4; ++r1) {
        float2 v0 = g[r1 * 4 + 0], v1 = g[r1 * 4 + 1],
               v2 = g[r1 * 4 + 2], v3 = g[r1 * 4 + 3];
        float t0x = v0.x + v2.x, t0y = v0.y + v2.y;
        float t1x = v0.x - v2.x, t1y = v0.y - v2.y;
        float t2x = v1.x + v3.x, t2y = v1.y + v3.y;
        float t3x = v1.x - v3.x, t3y = v1.y - v3.y;
        v[r1 + 0]  = make_float2(t0x + t2x, t0y + t2y);
        v[r1 + 4]  = make_float2(t1x - sg * t3y, t1y + sg * t3x);
        v[r1 + 8]  = make_float2(t0x - t2x, t0y - t2y);
        v[r1 + 12] = make_float2(t1x + sg * t3y, t1y - sg * t3x);
    }
}

__device__ __forceinline__ void twiddle_ladder(float2 w, float2 W[16]) {
    W[1] = w;
    W[2] = cmulc(W[1], W[1]);
    W[3] = cmulc(W[2], W[1]);
    W[4] = cmulc(W[2], W[2]);
    W[5] = cmulc(W[4], W[1]);
    W[6] = cmulc(W[4], W[2]);
    W[7] = cmulc(W[4], W[3]);
    W[8] = cmulc(W[4], W[4]);
    #pragma unroll
    for (int j = 1; j < 8; ++j) W[8 + j] = cmulc(W[8], W[j]);
}

template <int S>
__device__ __forceinline__ void fft4096(float2* __restrict__ NB,
                                        float2* __restrict__ LX, int tid)
{
    const float TWO_PI = 6.28318530717958647692f;
    float2 v[16];
    {
        const int ii = (tid & 0xF0) | ((tid ^ (tid >> 4)) & 0x0F);
        #pragma unroll
        for (int a = 0; a < 16; ++a) v[a] = NB[a * 256 + ii];
        dft16<S>(v);
        float c0, s0;
        __sincosf((float)S * TWO_PI * (float)tid * (1.f / 4096.f), &s0, &c0);
        float2 W[16];
        twiddle_ladder(make_float2(c0, s0), W);
        #pragma unroll
        for (int r2 = 1; r2 < 16; ++r2) v[r2] = cmulc(v[r2], W[r2]);
        #pragma unroll
        for (int r2 = 0; r2 < 16; ++r2) LX[r2 * 256 + tid] = v[r2];
    }
    __syncthreads();
    const int r = tid >> 4, t1 = tid & 15;
    {
        #pragma unroll
        for (int t2 = 0; t2 < 16; ++t2) v[t2] = LX[r * 256 + t2 * 16 + t1];
        dft16<S>(v);
        float c0, s0;
        __sincosf((float)S * TWO_PI * (float)t1 * (1.f / 256.f), &s0, &c0);
        float2 W[16];
        twiddle_ladder(make_float2(c0, s0), W);
        #pragma unroll
        for (int m = 1; m < 16; ++m) v[m] = cmulc(v[m], W[m]);
        __syncthreads();
        #pragma unroll
        for (int m = 0; m < 16; ++m) LX[r * 256 + m * 16 + (t1 ^ m)] = v[m];
    }
    __syncthreads();
    {
        const int m = tid & 15;
        #pragma unroll
        for (int q = 0; q < 16; ++q) v[q] = LX[r * 256 + m * 16 + (q ^ m)];
        dft16<S>(v);
        const int inner = (m * 16) | ((r ^ m) & 15);
        #pragma unroll
        for (int p = 0; p < 16; ++p) NB[p * 256 + inner] = v[p];
    }
    __syncthreads();
}

// ---------------------------------------------------------------------------
// FFT middle kernel, bf16 I/O. grid (96, 32), block 256.
// ---------------------------------------------------------------------------
__global__ __launch_bounds__(256) void fft_mid_kernel(
    unsigned short* __restrict__ ht,   // [B,192,4096] bf16 in/out
    const float* __restrict__ rmat,
    const float* __restrict__ imat,
    const float* __restrict__ rb,
    const float* __restrict__ ib)
{
    __shared__ float2 NB[4096];
    __shared__ float2 LX[4096];

    const int tid = threadIdx.x;
    const int pp  = blockIdx.x;
    const int b   = blockIdx.y;
    const int h1  = 2 * pp, h2 = 2 * pp + 1;
    unsigned short* row1 = ht + ((size_t)b * 192 + h1) * 4096;
    unsigned short* row2 = ht + ((size_t)b * 192 + h2) * 4096;

    #pragma unroll
    for (int i = 0; i < 2; ++i) {
        int nb = i * 2048 + tid * 8;
        uint4 v1 = *(const uint4*)(row1 + nb);
        uint4 v2 = *(const uint4*)(row2 + nb);
        const unsigned short* p1 = (const unsigned short*)&v1;
        const unsigned short* p2 = (const unsigned short*)&v2;
        int a = nb >> 8;
        #pragma unroll
        for (int j = 0; j < 8; ++j) {
            int t = (nb + j) & 255;
            int ii = (t & 0xF0) | ((t ^ (t >> 4)) & 0x0F);
            NB[a * 256 + ii] = make_float2(bf2f(p1[j]), bf2f(p2[j]));
        }
    }
    __syncthreads();

    fft4096<-1>(NB, LX, tid);

    const float rd1 = rmat[(size_t)h1 * 192 + h1], ig1 = imat[(size_t)h1 * 192 + h1];
    const float rd2 = rmat[(size_t)h2 * 192 + h2], ig2 = imat[(size_t)h2 * 192 + h2];
    const float rb1 = rb[h1], ib1 = ib[h1];
    const float rb2 = rb[h2], ib2 = ib[h2];

    for (int k = tid; k <= 2048; k += 256) {
        int m = (4096 - k) & 4095;
        float2 Fk = NB[NBIDX(k)], Fm = NB[NBIDX(m)];
        const float sc = 1.f / 128.f;
        float X1r = sc * (Fk.x + Fm.x), X1i = sc * (Fk.y - Fm.y);
        float X2r = sc * (Fk.y + Fm.y), X2i = sc * (Fm.x - Fk.x);
        float Z1kr = fmaxf(fmaf(X1r, rd1, fmaf(-X1i, ig1, rb1)), 0.f);
        float Z1ki = fmaxf(fmaf(X1i, rd1, fmaf( X1r, ig1, ib1)), 0.f);
        float Z1mr = fmaxf(fmaf(X1r, rd1, fmaf( X1i, ig1, rb1)), 0.f);
        float Z1mi = fmaxf(fmaf(-X1i, rd1, fmaf(X1r, ig1, ib1)), 0.f);
        float Z2kr = fmaxf(fmaf(X2r, rd2, fmaf(-X2i, ig2, rb2)), 0.f);
        float Z2ki = fmaxf(fmaf(X2i, rd2, fmaf( X2r, ig2, ib2)), 0.f);
        float Z2mr = fmaxf(fmaf(X2r, rd2, fmaf( X2i, ig2, rb2)), 0.f);
        float Z2mi = fmaxf(fmaf(-X2i, rd2, fmaf(X2r, ig2, ib2)), 0.f);
        float Gkx = 0.5f * ((Z1kr + Z1mr) - (Z2ki - Z2mi));
        float Gky = 0.5f * ((Z1ki - Z1mi) + (Z2kr + Z2mr));
        float Gmx = 0.5f * ((Z1mr + Z1kr) - (Z2mi - Z2ki));
        float Gmy = 0.5f * ((Z1mi - Z1ki) + (Z2mr + Z2kr));
        NB[NBIDX(k)] = make_float2(Gkx, Gky);
        NB[NBIDX(m)] = make_float2(Gmx, Gmy);
    }
    __syncthreads();

    fft4096<1>(NB, LX, tid);

    const float inv = 1.f / 64.f;
    #pragma unroll
    for (int i = 0; i < 2; ++i) {
        int nb = i * 2048 + tid * 8;
        uint4 v1, v2;
        unsigned short* p1 = (unsigned short*)&v1;
        unsigned short* p2 = (unsigned short*)&v2;
        int a = nb >> 8;
        #pragma unroll
        for (int j = 0; j < 8; ++j) {
            int t = (nb + j) & 255;
            int ii = (t & 0xF0) | ((t ^ (t >> 4)) & 0x0F);
            float2 g = NB[a * 256 + ii];
            p1[j] = f2bf(g.x * inv);
            p2[j] = f2bf(g.y * inv);
        }
        *(uint4*)(row1 + nb) = v1;
        *(uint4*)(row2 + nb) = v2;
    }
}

// ---------------------------------------------------------------------------
// Transpose: yT[b][tok][hc] = ht[b][hc][tok]. 64x64 tiles, block 256.
// grid (4096/64, 192/64, 32).
// ---------------------------------------------------------------------------
__global__ __launch_bounds__(256) void transpose_kernel(
    const unsigned short* __restrict__ ht,  // [B,192,4096]
    unsigned short* __restrict__ yT)        // [B,4096,192]
{
    __shared__ unsigned short tl[64][72];   // [tok][hc], pad 8

    const int tid  = threadIdx.x;
    const int tok0 = blockIdx.x * 64;
    const int hc0  = blockIdx.y * 64;
    const int b    = blockIdx.z;

    const unsigned short* src = ht + ((size_t)b * 192 + hc0) * 4096 + tok0;
    #pragma unroll
    for (int it = 0; it < 2; ++it) {
        int id = tid + it * 256;            // 0..511
        int hc = id >> 3, t8 = (id & 7) * 8;
        uint4 v = *(const uint4*)(src + (size_t)hc * 4096 + t8);
        const unsigned short* p = (const unsigned short*)&v;
        #pragma unroll
        for (int u = 0; u < 8; ++u) tl[t8 + u][hc] = p[u];
    }
    __syncthreads();

    unsigned short* dst = yT + ((size_t)b * 4096 + tok0) * 192 + hc0;
    #pragma unroll
    for (int it = 0; it < 2; ++it) {
        int id = tid + it * 256;
        int tok = id >> 3, h8 = (id & 7) * 8;
        uint4 v = *(uint4*)&tl[tok][h8];
        *(uint4*)(dst + (size_t)tok * 192 + h8) = v;
    }
}

// ---------------------------------------------------------------------------
// GEMM2 (MFMA): out[t][c] = bn2( sum_hc yT[t][hc] * w2[c][hc] ), t over B*N.
// m=tok(128/block), n=ch(96), K=192. A-frags straight from global (each
// element read exactly once); B = w2 rows from padded LDS. Standard
// fragment layouts only, no inline asm. grid 1024, block 256.
// ---------------------------------------------------------------------------
__global__ __launch_bounds__(256, 2) void gemm2_kernel(
    const unsigned short* __restrict__ yT,  // [B*4096, 192] bf16
    const float* __restrict__ w2,           // [96,192]
    const float* __restrict__ g2, const float* __restrict__ be2,
    const float* __restrict__ mu2, const float* __restrict__ va2,
    float* __restrict__ out)                // [B*4096, 96]
{
    __shared__ unsigned short w2s[96][200];   // [ch][K], pad 8 -> 38,400 B
    __shared__ float sb2[2][96];

    const int tid = threadIdx.x;
    const size_t T0 = (size_t)blockIdx.x * 128;
    const int lane = tid & 63, wid = tid >> 6;
    const int lm = lane & 15, lg = lane >> 4;

    if (tid < 96) {
        float s = g2[tid] * rsqrtf(va2[tid] + EPS);
        sb2[0][tid] = s;
        sb2[1][tid] = be2[tid] - mu2[tid] * s;
    }
    #pragma unroll
    for (int i = 0; i < 18; ++i) {
        int id = tid + i * 256;              // 4608 float4
        int ch = id / 48, k4 = (id % 48) * 4;
        float4 v = *(const float4*)(w2 + (size_t)ch * 192 + k4);
        ushort4 hv = { f2bf(v.x), f2bf(v.y), f2bf(v.z), f2bf(v.w) };
        *(ushort4*)&w2s[ch][k4] = hv;
    }
    __syncthreads();

    f32x4 acc[2][6];
    #pragma unroll
    for (int mf = 0; mf < 2; ++mf)
        #pragma unroll
        for (int nf = 0; nf < 6; ++nf) acc[mf][nf] = (f32x4){0.f, 0.f, 0.f, 0.f};

    const unsigned short* arow0 = yT + (T0 + (wid * 2 + 0) * 16 + lm) * 192;
    const unsigned short* arow1 = yT + (T0 + (wid * 2 + 1) * 16 + lm) * 192;

    #pragma unroll
    for (int ks = 0; ks < 6; ++ks) {
        const int k0 = ks * 32 + lg * 8;
        bf16x8 a0 = *(const bf16x8*)(arow0 + k0);
        bf16x8 a1 = *(const bf16x8*)(arow1 + k0);
        #pragma unroll
        for (int nf = 0; nf < 6; ++nf) {
            bf16x8 bfv = *(const bf16x8*)&w2s[nf * 16 + lm][k0];
            acc[0][nf] = __builtin_amdgcn_mfma_f32_16x16x32_bf16(a0, bfv, acc[0][nf], 0, 0, 0);
            acc[1][nf] = __builtin_amdgcn_mfma_f32_16x16x32_bf16(a1, bfv, acc[1][nf], 0, 0, 0);
        }
    }

    // epilogue: lane holds C[tok = (wid*2+mf)*16 + lg*4 + r][ch = nf*16 + lm]
    float* ob = out + T0 * 96;
    #pragma unroll
    for (int nf = 0; nf < 6; ++nf) {
        int ch = nf * 16 + lm;
        float s = sb2[0][ch], bb = sb2[1][ch];
        #pragma unroll
        for (int mf = 0; mf < 2; ++mf) {
            int tokb = (wid * 2 + mf) * 16 + lg * 4;
            #pragma unroll
            for (int r = 0; r < 4; ++r) {
                ob[(size_t)(tokb + r) * 96 + ch] = fmaf(acc[mf][nf][r], s, bb);
            }
        }
    }
}

// ---------------------------------------------------------------------------
extern "C" void kernel_launch(void* const* d_in, const int* in_sizes, int n_in,
                              void* d_out, int out_size, void* d_ws, size_t ws_size,
                              hipStream_t stream)
{
    const float* x   = (const float*)d_in[0];
    const float* w1  = (const float*)d_in[1];
    const float* g1  = (const float*)d_in[2];
    const float* be1 = (const float*)d_in[3];
    const float* mu1 = (const float*)d_in[4];
    const float* va1 = (const float*)d_in[5];
    const float* r   = (const float*)d_in[6];
    const float* im  = (const float*)d_in[7];
    const float* rb  = (const float*)d_in[8];
    const float* ib  = (const float*)d_in[9];
    const float* w2  = (const float*)d_in[10];
    const float* g2  = (const float*)d_in[11];
    const float* be2 = (const float*)d_in[12];
    const float* mu2 = (const float*)d_in[13];
    const float* va2 = (const float*)d_in[14];
    float* out = (float*)d_out;

    unsigned short* ht = (unsigned short*)d_ws;            // 50,331,648 B
    unsigned short* yT = ht + (size_t)32 * 192 * 4096;     // 50,331,648 B

    gemm1_kernel<<<dim3(1024), 256, 0, stream>>>(x, w1, g1, be1, mu1, va1, ht);
    fft_mid_kernel<<<dim3(96, 32), 256, 0, stream>>>(ht, r, im, rb, ib);
    transpose_kernel<<<dim3(64, 3, 32), 256, 0, stream>>>(ht, yT);
    gemm2_kernel<<<dim3(1024), 256, 0, stream>>>(yT, w2, g2, be2, mu2, va2, out);
}